// Round 1
// baseline (3361.384 us; speedup 1.0000x reference)
//
#include <hip/hip_runtime.h>

// ---------------------------------------------------------------------------
// SingleStreamBlock (DiT) on MI355X / gfx950.
// Round 0: correctness-first baseline with m97-structure bf16 MFMA GEMMs and
// an MFMA flash attention. All heavy compute in bf16 (threshold budgets it).
//
// Pipeline:
//  1) k_cvt      : w1 f32 -> bf16 (ws)
//  2) k_mod      : mod = silu(vec) @ mod_w^T + mod_b        (9216 f32)
//  3) k_lnmod    : xmod = (1+scale)*LN(x) + shift           (bf16)
//  4) k_gemm1    : h = xmod @ w1^T + b1 ; epilogue splits q/k/v ([H][L][HD])
//                  and writes gelu(mlp) ([L][MLP])          (bf16)
//  5) k_qkrope   : RMSNorm(q,k)*scale then RoPE (pe), in place
//  6) k_attn     : flash attention per (head, 64-q-row tile) -> attn [L][D]
//  7) k_cvt      : w2 f32 -> bf16 (aliases w1b region)
//  8) k_gemm2    : out = x + gate * (cat(attn, mlp) @ w2^T + b2)  (f32)
// ---------------------------------------------------------------------------

typedef __bf16 bf16;
typedef __bf16 bf16x2 __attribute__((ext_vector_type(2)));
typedef __bf16 bf16x4v __attribute__((ext_vector_type(4)));
typedef __bf16 bf16x8 __attribute__((ext_vector_type(8)));
typedef float  f32x4 __attribute__((ext_vector_type(4)));
typedef unsigned short u16;
typedef unsigned int   u32;

#define DEV static __device__ __forceinline__

constexpr int Lq   = 4096;
constexpr int Dm   = 3072;
constexpr int Hh   = 24;
constexpr int HDd  = 128;
constexpr int MLPd = 12288;
constexpr int N1   = 3*Dm + MLPd;   // 21504 (gemm1 N)
constexpr int K2   = Dm + MLPd;     // 15360 (gemm2 K)

// global -> LDS direct copy, 16B per lane, 1KiB per wave-call.
#define GLOAD16(gp, lp) __builtin_amdgcn_global_load_lds(                      \
    (const __attribute__((address_space(1))) void*)(gp),                       \
    (__attribute__((address_space(3))) void*)(lp), 16, 0, 0)

DEV f32x4 mfma_bf16(bf16x8 a, bf16x8 b, f32x4 c){
  return __builtin_amdgcn_mfma_f32_16x16x32_bf16(a, b, c, 0, 0, 0);
}

DEV u16 f2b(float f){ bf16 h = (bf16)f; return __builtin_bit_cast(u16, h); }

DEV float wave_sum(float v){
#pragma unroll
  for (int o = 32; o > 0; o >>= 1) v += __shfl_xor(v, o);
  return v;
}

// --------------------------------------------------------------------------
__global__ __launch_bounds__(256) void k_cvt(const float* __restrict__ s,
                                             bf16* __restrict__ d){
  size_t i = ((size_t)blockIdx.x*256 + threadIdx.x)*4;
  float4 v = *(const float4*)(s + i);
  bf16x4v o; o[0]=(bf16)v.x; o[1]=(bf16)v.y; o[2]=(bf16)v.z; o[3]=(bf16)v.w;
  *(bf16x4v*)(d + i) = o;
}

// --------------------------------------------------------------------------
__global__ __launch_bounds__(256) void k_mod(const float* __restrict__ vec,
                                             const float* __restrict__ mw,
                                             const float* __restrict__ mb,
                                             float* __restrict__ mod){
  const int row = blockIdx.x, tid = threadIdx.x;
  const float* wr = mw + (size_t)row*Dm;
  float a = 0.f;
  for (int k = tid; k < Dm; k += 256){
    float vv = vec[k];
    a += (vv / (1.f + __expf(-vv))) * wr[k];
  }
  a = wave_sum(a);
  __shared__ float red[4];
  if ((tid & 63) == 0) red[tid >> 6] = a;
  __syncthreads();
  if (tid == 0) mod[row] = red[0]+red[1]+red[2]+red[3] + mb[row];
}

// --------------------------------------------------------------------------
__global__ __launch_bounds__(256) void k_lnmod(const float* __restrict__ x,
                                               const float* __restrict__ mod,
                                               bf16* __restrict__ xmod){
  const int row = blockIdx.x, tid = threadIdx.x;
  const float* xr = x + (size_t)row*Dm;
  float v[12]; float s = 0.f, s2 = 0.f;
#pragma unroll
  for (int i = 0; i < 12; i++){ v[i] = xr[tid + i*256]; s += v[i]; s2 += v[i]*v[i]; }
  s = wave_sum(s); s2 = wave_sum(s2);
  __shared__ float rs[4], rs2[4];
  if ((tid & 63) == 0){ rs[tid>>6] = s; rs2[tid>>6] = s2; }
  __syncthreads();
  float S  = rs[0]+rs[1]+rs[2]+rs[3];
  float S2 = rs2[0]+rs2[1]+rs2[2]+rs2[3];
  const float mu  = S * (1.f/Dm);
  const float var = S2 * (1.f/Dm) - mu*mu;
  const float rr  = rsqrtf(var + 1e-6f);
#pragma unroll
  for (int i = 0; i < 12; i++){
    int d = tid + i*256;
    xmod[(size_t)row*Dm + d] = (bf16)((v[i]-mu)*rr*(1.f + mod[Dm + d]) + mod[d]);
  }
}

// --------------------------------------------------------------------------
// GEMM1: A = xmod [4096][3072] bf16, B = w1b [21504][3072] bf16 (B^T layout).
// m97 structure: 128x128 tile, BK=32, 4 waves (2x2), 4x4 16x16x32 frags/wave.
__global__ __launch_bounds__(256) void k_gemm1(const bf16* __restrict__ A,
                                               const bf16* __restrict__ B,
                                               const float* __restrict__ b1,
                                               bf16* __restrict__ qb,
                                               bf16* __restrict__ kb,
                                               bf16* __restrict__ vb,
                                               bf16* __restrict__ mlpb){
  __shared__ alignas(16) bf16 As[128*32], Bs[128*32];
  const int tid = threadIdx.x, lane = tid & 63, w = tid >> 6;
  const int wm = w >> 1, wn = w & 1;
  const int q16 = lane & 15, g = lane >> 4;
  const int m0 = blockIdx.y*128, n0 = blockIdx.x*128;
  const int srow = lane >> 2, scol = (lane & 3)*8;
  f32x4 acc[4][4];
#pragma unroll
  for (int i = 0; i < 4; i++)
#pragma unroll
    for (int j = 0; j < 4; j++) acc[i][j] = 0.f;
  const bf16* ga = A + (size_t)(m0 + srow)*Dm + scol;
  const bf16* gb = B + (size_t)(n0 + srow)*Dm + scol;
  for (int k0 = 0; k0 < Dm; k0 += 32){
    __syncthreads();
    GLOAD16(ga + (size_t)(w*32     )*Dm + k0, As + (w*32     )*32);
    GLOAD16(ga + (size_t)(w*32 + 16)*Dm + k0, As + (w*32 + 16)*32);
    GLOAD16(gb + (size_t)(w*32     )*Dm + k0, Bs + (w*32     )*32);
    GLOAD16(gb + (size_t)(w*32 + 16)*Dm + k0, Bs + (w*32 + 16)*32);
    __syncthreads();
    bf16x8 af[4], bfr[4];
#pragma unroll
    for (int i = 0; i < 4; i++) af[i]  = *(const bf16x8*)(As + (wm*64 + i*16 + q16)*32 + g*8);
#pragma unroll
    for (int j = 0; j < 4; j++) bfr[j] = *(const bf16x8*)(Bs + (wn*64 + j*16 + q16)*32 + g*8);
#pragma unroll
    for (int i = 0; i < 4; i++)
#pragma unroll
      for (int j = 0; j < 4; j++)
        acc[i][j] = mfma_bf16(af[i], bfr[j], acc[i][j]);
  }
  // epilogue: split qkv -> [H][L][HD], gelu(mlp) -> [L][MLP]
#pragma unroll
  for (int i = 0; i < 4; i++){
#pragma unroll
    for (int j = 0; j < 4; j++){
      const int col  = n0 + wn*64 + j*16 + q16;
      const float bias = b1[col];
      const int rowb = m0 + wm*64 + i*16 + g*4;
#pragma unroll
      for (int r = 0; r < 4; r++){
        float val = acc[i][j][r] + bias;
        int m = rowb + r;
        if (col < 3*Dm){
          bf16* dst = (col < Dm) ? qb : (col < 2*Dm) ? kb : vb;
          int cc = (col < Dm) ? col : (col < 2*Dm) ? col - Dm : col - 2*Dm;
          dst[((size_t)(cc >> 7)*Lq + m)*HDd + (cc & 127)] = (bf16)val;
        } else {
          float t  = val*(0.7978845608028654f + 0.0356774081f*val*val);
          float gl = 0.5f*val*(1.f + tanhf(t));
          mlpb[(size_t)m*MLPd + (col - 3*Dm)] = (bf16)gl;
        }
      }
    }
  }
}

// --------------------------------------------------------------------------
// RMSNorm + RoPE in place on q,k ([H][L][HD]); one wave per 128-elem row.
__global__ __launch_bounds__(256) void k_qkrope(bf16* __restrict__ qb,
                                                bf16* __restrict__ kb,
                                                const float* __restrict__ qs,
                                                const float* __restrict__ ks,
                                                const float* __restrict__ pe){
  const int lane = threadIdx.x & 63;
  const int rid  = blockIdx.x*4 + (threadIdx.x >> 6);
  const bool isq = rid < Hh*Lq;
  const int hl   = isq ? rid : rid - Hh*Lq;
  bf16* buf = (isq ? qb : kb) + (size_t)hl*HDd + lane*2;
  const float* sc = isq ? qs : ks;
  const int l = hl & (Lq - 1);
  bf16x2 t = *(const bf16x2*)buf;
  float t0 = (float)t[0], t1 = (float)t[1];
  float ss = wave_sum(t0*t0 + t1*t1);
  float rr = rsqrtf(ss*(1.f/HDd) + 1e-6f);
  float n0v = t0*rr*sc[lane*2], n1v = t1*rr*sc[lane*2+1];
  float4 p4 = *(const float4*)(pe + ((size_t)l*64 + lane)*4);  // [c,-s,s,c]
  bf16x2 o;
  o[0] = (bf16)(p4.x*n0v + p4.y*n1v);
  o[1] = (bf16)(p4.z*n0v + p4.w*n1v);
  *(bf16x2*)buf = o;
}

// --------------------------------------------------------------------------
// Flash attention. Block = (head, 64 q rows), 4 waves x 16 q rows.
// S^T = K·Q^T (swapped operands) so softmax reduce = in-lane + 2 shuffles.
// P^T bounced via LDS -> PV B-operand; V staged transposed for A-operand.
__global__ __launch_bounds__(256) void k_attn(const bf16* __restrict__ qb,
                                              const bf16* __restrict__ kb,
                                              const bf16* __restrict__ vb,
                                              bf16* __restrict__ attn){
  __shared__ alignas(16) bf16 Kt[32*128];   // [key][hd]
  __shared__ alignas(16) bf16 Vt[128*32];   // [hd][key] (transposed)
  __shared__ alignas(16) bf16 Pl[4][16*32]; // per wave: [q][key]
  const int tid = threadIdx.x, lane = tid & 63, w = tid >> 6;
  const int q16 = lane & 15, g = lane >> 4;
  const int head = blockIdx.y, qt = blockIdx.x;
  const size_t hoff = (size_t)head * Lq * HDd;
  const bf16* qrow = qb + hoff + (size_t)(qt*64 + w*16 + q16)*HDd;
  bf16x8 qf[4];
#pragma unroll
  for (int c = 0; c < 4; c++) qf[c] = *(const bf16x8*)(qrow + c*32 + g*8);
  f32x4 o[8];
#pragma unroll
  for (int n = 0; n < 8; n++) o[n] = 0.f;
  float mx = -3e38f, lsum = 0.f;

  for (int kt = 0; kt < Lq/32; kt++){
    __syncthreads();
    const bf16* kg = kb + hoff + (size_t)(kt*32)*HDd;
#pragma unroll
    for (int j = 0; j < 2; j++){
      int rb = w*8 + j*4;
      GLOAD16(kg + (size_t)(rb + g)*HDd + q16*8, Kt + rb*128);
    }
#pragma unroll
    for (int j = 0; j < 2; j++){
      int e = tid*8 + j*2048;
      int r = e >> 7, c = e & 127;
      bf16x8 vv = *(const bf16x8*)(vb + hoff + (size_t)(kt*32 + r)*HDd + c);
#pragma unroll
      for (int u = 0; u < 8; u++) Vt[(c+u)*32 + r] = vv[u];
    }
    __syncthreads();
    f32x4 s[2];
#pragma unroll
    for (int t2 = 0; t2 < 2; t2++){
      s[t2] = 0.f;
#pragma unroll
      for (int c = 0; c < 4; c++){
        bf16x8 kf = *(const bf16x8*)(Kt + (t2*16 + q16)*128 + c*32 + g*8);
        s[t2] = mfma_bf16(kf, qf[c], s[t2]);
      }
    }
    float tm = -3e38f;
#pragma unroll
    for (int t2 = 0; t2 < 2; t2++)
#pragma unroll
      for (int r = 0; r < 4; r++){
        s[t2][r] *= 0.088388347648318447f;  // 1/sqrt(128)
        tm = fmaxf(tm, s[t2][r]);
      }
    tm = fmaxf(tm, __shfl_xor(tm, 16));
    tm = fmaxf(tm, __shfl_xor(tm, 32));
    float mnew = fmaxf(mx, tm);
    float corr = __expf(mx - mnew);
    float ps = 0.f;
    u16 pb[8];
#pragma unroll
    for (int t2 = 0; t2 < 2; t2++)
#pragma unroll
      for (int r = 0; r < 4; r++){
        float p = __expf(s[t2][r] - mnew);
        ps += p;
        pb[t2*4+r] = f2b(p);
      }
    ps += __shfl_xor(ps, 16);
    ps += __shfl_xor(ps, 32);
    lsum = lsum*corr + ps;
    mx = mnew;
#pragma unroll
    for (int n = 0; n < 8; n++)
#pragma unroll
      for (int r = 0; r < 4; r++) o[n][r] *= corr;
#pragma unroll
    for (int t2 = 0; t2 < 2; t2++)
      *(ushort4*)(&Pl[w][q16*32 + t2*16 + g*4]) =
          make_ushort4(pb[t2*4], pb[t2*4+1], pb[t2*4+2], pb[t2*4+3]);
    bf16x8 pf = *(const bf16x8*)(&Pl[w][q16*32 + g*8]);
#pragma unroll
    for (int n = 0; n < 8; n++){
      bf16x8 vf = *(const bf16x8*)(Vt + (n*16 + q16)*32 + g*8);
      o[n] = mfma_bf16(vf, pf, o[n]);   // O^T += V^T · P^T
    }
  }
  float inv = 1.f / lsum;
  const int row = qt*64 + w*16 + q16;
#pragma unroll
  for (int n = 0; n < 8; n++){
    u16 ov[4];
#pragma unroll
    for (int r = 0; r < 4; r++) ov[r] = f2b(o[n][r]*inv);
    *(ushort4*)(attn + (size_t)row*Dm + head*HDd + n*16 + g*4) =
        make_ushort4(ov[0], ov[1], ov[2], ov[3]);
  }
}

// --------------------------------------------------------------------------
// GEMM2: A = cat(attn [L][D], gelu_mlp [L][MLP]) bf16, B = w2b [3072][15360].
// Epilogue: out = x + gate*(acc + b2)   (f32)
__global__ __launch_bounds__(256) void k_gemm2(const bf16* __restrict__ attn,
                                               const bf16* __restrict__ mlpb,
                                               const bf16* __restrict__ B,
                                               const float* __restrict__ b2,
                                               const float* __restrict__ x,
                                               const float* __restrict__ mod,
                                               float* __restrict__ out){
  __shared__ alignas(16) bf16 As[128*32], Bs[128*32];
  const int tid = threadIdx.x, lane = tid & 63, w = tid >> 6;
  const int wm = w >> 1, wn = w & 1;
  const int q16 = lane & 15, g = lane >> 4;
  const int m0 = blockIdx.y*128, n0 = blockIdx.x*128;
  const int srow = lane >> 2, scol = (lane & 3)*8;
  f32x4 acc[4][4];
#pragma unroll
  for (int i = 0; i < 4; i++)
#pragma unroll
    for (int j = 0; j < 4; j++) acc[i][j] = 0.f;
  for (int k0 = 0; k0 < K2; k0 += 32){
    __syncthreads();
#pragma unroll
    for (int j = 0; j < 2; j++){
      int row = m0 + w*32 + j*16 + srow;
      const bf16* gA = (k0 < Dm)
          ? (attn + (size_t)row*Dm   + k0        + scol)
          : (mlpb + (size_t)row*MLPd + (k0 - Dm) + scol);
      GLOAD16(gA, As + (w*32 + j*16)*32);
      GLOAD16(B + (size_t)(n0 + w*32 + j*16 + srow)*K2 + k0 + scol,
              Bs + (w*32 + j*16)*32);
    }
    __syncthreads();
    bf16x8 af[4], bfr[4];
#pragma unroll
    for (int i = 0; i < 4; i++) af[i]  = *(const bf16x8*)(As + (wm*64 + i*16 + q16)*32 + g*8);
#pragma unroll
    for (int j = 0; j < 4; j++) bfr[j] = *(const bf16x8*)(Bs + (wn*64 + j*16 + q16)*32 + g*8);
#pragma unroll
    for (int i = 0; i < 4; i++)
#pragma unroll
      for (int j = 0; j < 4; j++)
        acc[i][j] = mfma_bf16(af[i], bfr[j], acc[i][j]);
  }
#pragma unroll
  for (int i = 0; i < 4; i++){
#pragma unroll
    for (int j = 0; j < 4; j++){
      const int col = n0 + wn*64 + j*16 + q16;
      const float bias = b2[col];
      const float gate = mod[2*Dm + col];
      const int rowb = m0 + wm*64 + i*16 + g*4;
#pragma unroll
      for (int r = 0; r < 4; r++){
        int m = rowb + r;
        float val = acc[i][j][r] + bias;
        out[(size_t)m*Dm + col] = x[(size_t)m*Dm + col] + gate*val;
      }
    }
  }
}

// --------------------------------------------------------------------------
extern "C" void kernel_launch(void* const* d_in, const int* in_sizes, int n_in,
                              void* d_out, int out_size, void* d_ws, size_t ws_size,
                              hipStream_t stream){
  const float* x       = (const float*)d_in[0];
  const float* vec     = (const float*)d_in[1];
  const float* pe      = (const float*)d_in[2];
  const float* w1      = (const float*)d_in[3];
  const float* b1      = (const float*)d_in[4];
  const float* w2      = (const float*)d_in[5];
  const float* b2      = (const float*)d_in[6];
  const float* mod_w   = (const float*)d_in[7];
  const float* mod_b   = (const float*)d_in[8];
  const float* q_scale = (const float*)d_in[9];
  const float* k_scale = (const float*)d_in[10];
  float* out = (float*)d_out;
  char* ws = (char*)d_ws;

  // workspace layout (bytes); w2b aliases w1b, attn aliases xmod (stream-ordered)
  const size_t OFF_MOD  = 0;                        // 36864
  const size_t OFF_XMOD = 36864;                    // 25165824 (xmod, later attn)
  const size_t OFF_W1B  = OFF_XMOD + 25165824ull;   // 132120576 (w1b, later w2b)
  const size_t OFF_Q    = OFF_W1B + 132120576ull;   // 25165824
  const size_t OFF_K    = OFF_Q   + 25165824ull;
  const size_t OFF_V    = OFF_K   + 25165824ull;
  const size_t OFF_MLP  = OFF_V   + 25165824ull;    // 100663296  (total ~334MB)

  float* modp  = (float*)(ws + OFF_MOD);
  bf16*  xmod  = (bf16*)(ws + OFF_XMOD);
  bf16*  attnb = (bf16*)(ws + OFF_XMOD);  // alias (xmod dead after gemm1)
  bf16*  w1b   = (bf16*)(ws + OFF_W1B);
  bf16*  w2b   = (bf16*)(ws + OFF_W1B);   // alias (w1b dead after gemm1)
  bf16*  qbuf  = (bf16*)(ws + OFF_Q);
  bf16*  kbuf  = (bf16*)(ws + OFF_K);
  bf16*  vbuf  = (bf16*)(ws + OFF_V);
  bf16*  mlpb  = (bf16*)(ws + OFF_MLP);

  k_cvt   <<<64512, 256, 0, stream>>>(w1, w1b);                 // 66060288 elems
  k_mod   <<<9216,  256, 0, stream>>>(vec, mod_w, mod_b, modp);
  k_lnmod <<<4096,  256, 0, stream>>>(x, modp, xmod);
  k_gemm1 <<<dim3(N1/128, Lq/128), 256, 0, stream>>>(xmod, w1b, b1, qbuf, kbuf, vbuf, mlpb);
  k_qkrope<<<(2*Hh*Lq)/4, 256, 0, stream>>>(qbuf, kbuf, q_scale, k_scale, pe);
  k_attn  <<<dim3(Lq/64, Hh), 256, 0, stream>>>(qbuf, kbuf, vbuf, attnb);
  k_cvt   <<<46080, 256, 0, stream>>>(w2, w2b);                 // 47185920 elems
  k_gemm2 <<<dim3(Dm/128, Lq/128), 256, 0, stream>>>(attnb, mlpb, w2b, b2, x, modp, out);
}